// Round 1
// baseline (1770.028 us; speedup 1.0000x reference)
//
#include <hip/hip_runtime.h>

// MoE ConvNeXt block: dwconv7x7 -> LN -> top2 router w/ capacity -> expert MLP (bf16 MFMA) -> combine
// Shapes: N=64 C=384 H=W=32 -> T=65536, E=8, K=2, Hd=1536, Be=13107, Bp=13184 (=103*128)
// ws usage ~318 MB (hid reused across 2 groups of 4 experts).

typedef unsigned int u32;
typedef unsigned short u16;
typedef __attribute__((ext_vector_type(8))) __bf16 bf16x8;
typedef __attribute__((ext_vector_type(4))) float f32x4;

#define T_TOK 65536
#define C_DIM 384
#define HD 1536
#define BE 13107
#define BP 13184

__device__ __forceinline__ u16 f2bf(float f) {
  u32 u = __float_as_uint(f);
  u32 r = (u + 0x7FFFu + ((u >> 16) & 1u)) >> 16;
  return (u16)r;
}
__device__ __forceinline__ float bf2f(u16 b) { return __uint_as_float(((u32)b) << 16); }

// ---------------- depthwise conv 7x7 (one (n,c) plane per block) ----------------
__global__ __launch_bounds__(256) void k_conv(const float* __restrict__ x,
                                              const float* __restrict__ cw,
                                              const float* __restrict__ cb,
                                              float* __restrict__ hconv) {
  __shared__ float xp[38 * 40];  // padded plane: rows y+3 in [0,38), cols x+3 in [0,40)
  __shared__ float cwl[49];
  int b = blockIdx.x;            // n*384 + c
  int c = b % 384;
  int tid = threadIdx.x;
  for (int i = tid; i < 1520; i += 256) xp[i] = 0.0f;
  if (tid < 49) cwl[tid] = cw[tid * 384 + c];
  __syncthreads();
  const float* xsrc = x + (size_t)b * 1024;
  {
    float4 v = *(const float4*)&xsrc[tid * 4];
    int yy = tid >> 3, xx = (tid & 7) * 4;
    float* d = &xp[(yy + 3) * 40 + xx + 3];
    d[0] = v.x; d[1] = v.y; d[2] = v.z; d[3] = v.w;
  }
  __syncthreads();
  int ty = tid >> 3, w0 = (tid & 7) * 4;
  float bias = cb[c];
  float o0 = bias, o1 = bias, o2 = bias, o3 = bias;
#pragma unroll
  for (int dy = 0; dy < 7; dy++) {
    const float* row = &xp[(ty + dy) * 40 + w0];
    float4 A = *(const float4*)row;
    float4 B = *(const float4*)(row + 4);
    float4 Cc = *(const float4*)(row + 8);
    float v0 = A.x, v1 = A.y, v2 = A.z, v3 = A.w;
    float v4 = B.x, v5 = B.y, v6 = B.z, v7 = B.w;
    float v8 = Cc.x, v9 = Cc.y;
    const float* wrow = &cwl[dy * 7];
    float wt;
    wt = wrow[0]; o0 += wt * v0; o1 += wt * v1; o2 += wt * v2; o3 += wt * v3;
    wt = wrow[1]; o0 += wt * v1; o1 += wt * v2; o2 += wt * v3; o3 += wt * v4;
    wt = wrow[2]; o0 += wt * v2; o1 += wt * v3; o2 += wt * v4; o3 += wt * v5;
    wt = wrow[3]; o0 += wt * v3; o1 += wt * v4; o2 += wt * v5; o3 += wt * v6;
    wt = wrow[4]; o0 += wt * v4; o1 += wt * v5; o2 += wt * v6; o3 += wt * v7;
    wt = wrow[5]; o0 += wt * v5; o1 += wt * v6; o2 += wt * v7; o3 += wt * v8;
    wt = wrow[6]; o0 += wt * v6; o1 += wt * v7; o2 += wt * v8; o3 += wt * v9;
  }
  float4 ov = {o0, o1, o2, o3};
  *(float4*)&hconv[(size_t)b * 1024 + ty * 32 + w0] = ov;
}

// ---------------- LayerNorm (over C) + bf16 cast; block = one (n,y) row of 32 tokens ----------------
__global__ __launch_bounds__(256) void k_ln(const float* __restrict__ hconv,
                                            const float* __restrict__ lng,
                                            const float* __restrict__ lnb,
                                            u16* __restrict__ xln) {
  __shared__ float tile[384 * 33];  // [c][w], stride 33 to break bank conflicts
  int nb = blockIdx.x;              // n*32 + y
  int n = nb >> 5, y = nb & 31;
  int tid = threadIdx.x;
  const float* src = hconv + (size_t)n * 384 * 1024 + (y << 5);
  for (int i = tid; i < 12288; i += 256) {
    int c = i >> 5, w = i & 31;
    tile[c * 33 + w] = src[(size_t)c * 1024 + w];
  }
  __syncthreads();
  int wv = tid >> 6, lane = tid & 63;
  for (int w = wv; w < 32; w += 4) {
    float v[6];
    float s = 0.f, s2 = 0.f;
#pragma unroll
    for (int k = 0; k < 6; k++) {
      float t = tile[(lane + (k << 6)) * 33 + w];
      v[k] = t; s += t; s2 += t * t;
    }
#pragma unroll
    for (int off = 32; off > 0; off >>= 1) {
      s += __shfl_xor(s, off, 64);
      s2 += __shfl_xor(s2, off, 64);
    }
    float mu = s * (1.0f / 384.0f);
    float var = s2 * (1.0f / 384.0f) - mu * mu;
    float r = rsqrtf(var + 1e-6f);
    size_t t0 = ((size_t)nb << 5) + w;  // token index
#pragma unroll
    for (int k = 0; k < 6; k++) {
      int c = lane + (k << 6);
      float o = (v[k] - mu) * r * lng[c] + lnb[c];
      xln[t0 * 384 + c] = f2bf(o);
    }
  }
}

// ---------------- router: logits(8), softmax max -> priority key, top2 + gates ----------------
__global__ __launch_bounds__(256) void k_router(const u16* __restrict__ xln,
                                                const float* __restrict__ gw,
                                                u32* __restrict__ keys, u32* __restrict__ vals,
                                                u32* __restrict__ topi,
                                                float* __restrict__ g1, float* __restrict__ g2) {
  __shared__ float gwl[8 * 384];
  int tid = threadIdx.x;
  for (int i = tid; i < 3072; i += 256) gwl[i] = gw[i];
  __syncthreads();
  int wv = tid >> 6, lane = tid & 63;
  int t = (blockIdx.x << 2) + wv;
  float acc[8] = {0, 0, 0, 0, 0, 0, 0, 0};
#pragma unroll
  for (int k = 0; k < 6; k++) {
    int c = lane + (k << 6);
    float xv = bf2f(xln[(size_t)t * 384 + c]);
#pragma unroll
    for (int e = 0; e < 8; e++) acc[e] += xv * gwl[e * 384 + c];
  }
#pragma unroll
  for (int off = 32; off > 0; off >>= 1) {
#pragma unroll
    for (int e = 0; e < 8; e++) acc[e] += __shfl_xor(acc[e], off, 64);
  }
  if (lane == 0) {
    float v1 = -1e30f, v2 = -1e30f;
    int e1 = 0, e2 = 0;
#pragma unroll
    for (int e = 0; e < 8; e++) {
      float l = acc[e];
      if (l > v1) { v2 = v1; e2 = e1; v1 = l; e1 = e; }
      else if (l > v2) { v2 = l; e2 = e; }
    }
    float sum = 0.f;
#pragma unroll
    for (int e = 0; e < 8; e++) sum += __expf(acc[e] - v1);
    float p = 1.0f / sum;               // = max softmax prob
    float ew = __expf(v2 - v1);
    float w1 = 1.0f / (1.0f + ew);
    keys[t] = ~__float_as_uint(p);      // ascending sort == descending priority, stable
    vals[t] = (u32)t;
    topi[t] = (u32)e1 | ((u32)e2 << 8);
    g1[t] = w1;
    g2[t] = ew * w1;
  }
}

// ---------------- stable counting-sort machinery (8-bit digit) ----------------
__global__ __launch_bounds__(256) void k_hist(const u32* __restrict__ keys,
                                              u32* __restrict__ hist, int shift) {
  __shared__ u32 h[256];
  int tid = threadIdx.x;
  h[tid] = 0;
  __syncthreads();
  u32 key = keys[((size_t)blockIdx.x << 8) + tid];
  atomicAdd(&h[(key >> shift) & 255u], 1u);
  __syncthreads();
  hist[(size_t)tid * gridDim.x + blockIdx.x] = h[tid];
}

__global__ __launch_bounds__(256) void k_scan(u32* __restrict__ data, int n) {
  __shared__ u32 ls[256];
  int tid = threadIdx.x;
  int seg = n >> 8;
  int base = tid * seg;
  u32 s = 0;
  for (int i = 0; i < seg; i++) s += data[base + i];
  ls[tid] = s;
  __syncthreads();
  for (int d = 1; d < 256; d <<= 1) {
    u32 v = (tid >= d) ? ls[tid - d] : 0u;
    __syncthreads();
    ls[tid] += v;
    __syncthreads();
  }
  u32 run = (tid > 0) ? ls[tid - 1] : 0u;
  for (int i = 0; i < seg; i++) {
    u32 tmp = data[base + i];
    data[base + i] = run;
    run += tmp;
  }
}

__global__ __launch_bounds__(256) void k_scatter(const u32* __restrict__ kin,
                                                 const u32* __restrict__ vin,
                                                 u32* __restrict__ kout, u32* __restrict__ vout,
                                                 const u32* __restrict__ scanned, int shift) {
  __shared__ u32 dg[256];
  int tid = threadIdx.x;
  int g = (blockIdx.x << 8) + tid;
  u32 key = kin[g], val = vin[g];
  u32 d = (key >> shift) & 255u;
  dg[tid] = d;
  __syncthreads();
  u32 lr = 0;
  for (int j = 0; j < tid; j++) lr += (dg[j] == d) ? 1u : 0u;
  u32 pos = scanned[(size_t)d * gridDim.x + blockIdx.x] + lr;
  kout[pos] = key;
  vout[pos] = val;
}

// build k-major entry list over priority-sorted tokens
__global__ __launch_bounds__(256) void k_entries(const u32* __restrict__ order,
                                                 const u32* __restrict__ topi,
                                                 const float* __restrict__ g1,
                                                 const float* __restrict__ g2,
                                                 u32* __restrict__ ee, u32* __restrict__ et,
                                                 float* __restrict__ eg) {
  int m = (blockIdx.x << 8) + threadIdx.x;
  int i = m & 65535, k = m >> 16;
  u32 tok = order[i];
  u32 pk = topi[tok];
  ee[m] = k ? ((pk >> 8) & 255u) : (pk & 255u);
  et[m] = tok;
  eg[m] = k ? g2[tok] : g1[tok];
}

// stable counting sort by expert + capacity truncation -> dispatch tables + inverse map
__global__ __launch_bounds__(256) void k_dispatch(const u32* __restrict__ ee,
                                                  const u32* __restrict__ et,
                                                  const float* __restrict__ eg,
                                                  const u32* __restrict__ scanned,
                                                  int* __restrict__ dtok, float* __restrict__ dgate,
                                                  int* __restrict__ inv) {
  __shared__ u32 dg[256];
  int tid = threadIdx.x;
  int m = (blockIdx.x << 8) + tid;
  u32 e = ee[m];
  dg[tid] = e;
  __syncthreads();
  u32 lr = 0;
  for (int j = 0; j < tid; j++) lr += (dg[j] == e) ? 1u : 0u;
  u32 gpos = scanned[(size_t)e * gridDim.x + blockIdx.x] + lr;
  u32 start = scanned[(size_t)e * gridDim.x];
  u32 pos = gpos - start;
  if (pos < (u32)BE) {
    int slot = (int)e * BP + (int)pos;
    dtok[slot] = (int)et[m];
    dgate[slot] = eg[m];
    inv[et[m] * 2 + (m >> 16)] = slot;
  }
}

// ---------------- fp32 -> bf16 transposed weight prep: in [E][R][S] -> out [E][S][R] ----------------
__global__ __launch_bounds__(256) void k_transpose_bf16(const float* __restrict__ in,
                                                        u16* __restrict__ out, int R, int S) {
  __shared__ float t[32][33];
  int e = blockIdx.z;
  const float* ip = in + (size_t)e * R * S;
  u16* op = out + (size_t)e * R * S;
  int s0 = blockIdx.x << 5, r0 = blockIdx.y << 5;
  int tx = threadIdx.x, ty = threadIdx.y;
#pragma unroll
  for (int i = 0; i < 4; i++) {
    int r = r0 + ty + (i << 3);
    t[ty + (i << 3)][tx] = ip[(size_t)r * S + s0 + tx];
  }
  __syncthreads();
#pragma unroll
  for (int i = 0; i < 4; i++) {
    int s = s0 + ty + (i << 3);
    op[(size_t)s * R + r0 + tx] = f2bf(t[tx][ty + (i << 3)]);
  }
}

// ---------------- GEMM1: hid = gelu(gather(xln) @ w1 + b1), 128x128x32 MFMA tiles ----------------
__global__ __launch_bounds__(256) void k_gemm1(const u16* __restrict__ xln,
                                               const u16* __restrict__ w1t,
                                               const float* __restrict__ b1,
                                               const int* __restrict__ dtok,
                                               u16* __restrict__ hid, int e0) {
  __shared__ __align__(16) char smem[35072];  // staging 16KB; reused as 128x136 bf16 repack
  short* As = (short*)smem;
  short* Bs = (short*)(smem + 8192);
  int tid = threadIdx.x;
  int bx = blockIdx.x, by = blockIdx.y, z = blockIdx.z;
  int e = e0 + z;
  int f1 = tid, f2 = tid + 256;
  int m1 = ((f1 >> 6) << 4) | (f1 & 15), kq1 = (f1 >> 4) & 3;
  int m2 = ((f2 >> 6) << 4) | (f2 & 15), kq2 = (f2 >> 4) & 3;
  int dbase = e * BP + (bx << 7);
  int tokA1 = dtok[dbase + m1];
  int tokA2 = dtok[dbase + m2];
  const u16* a1p = xln + (size_t)tokA1 * 384 + kq1 * 8;
  const u16* a2p = xln + (size_t)tokA2 * 384 + kq2 * 8;
  const u16* bb = w1t + ((size_t)e * HD + (by << 7)) * 384;
  const u16* bp1 = bb + (size_t)m1 * 384 + kq1 * 8;
  const u16* bp2 = bb + (size_t)m2 * 384 + kq2 * 8;
  int wv = tid >> 6, lane = tid & 63;
  int wm = wv & 1, wn = wv >> 1;
  f32x4 acc[4][4];
#pragma unroll
  for (int i = 0; i < 4; i++)
#pragma unroll
    for (int j = 0; j < 4; j++) acc[i][j] = (f32x4){0.f, 0.f, 0.f, 0.f};
  for (int kk = 0; kk < 12; kk++) {
    *(uint4*)&As[f1 * 8] = *(const uint4*)(a1p + kk * 32);
    *(uint4*)&As[f2 * 8] = *(const uint4*)(a2p + kk * 32);
    *(uint4*)&Bs[f1 * 8] = *(const uint4*)(bp1 + kk * 32);
    *(uint4*)&Bs[f2 * 8] = *(const uint4*)(bp2 + kk * 32);
    __syncthreads();
    bf16x8 af[4], bfr[4];
#pragma unroll
    for (int i = 0; i < 4; i++) af[i] = *(const bf16x8*)&As[((((wm << 2) + i) << 6) | lane) * 8];
#pragma unroll
    for (int j = 0; j < 4; j++) bfr[j] = *(const bf16x8*)&Bs[((((wn << 2) + j) << 6) | lane) * 8];
#pragma unroll
    for (int i = 0; i < 4; i++)
#pragma unroll
      for (int j = 0; j < 4; j++)
        acc[i][j] = __builtin_amdgcn_mfma_f32_16x16x32_bf16(af[i], bfr[j], acc[i][j], 0, 0, 0);
    __syncthreads();
  }
  int quad = lane >> 4, c15 = lane & 15;
  u16* rp = (u16*)smem;  // [128][136]
#pragma unroll
  for (int j = 0; j < 4; j++) {
    int col = (((wn << 2) + j) << 4) | c15;
    float bias = b1[e * HD + (by << 7) + col];
#pragma unroll
    for (int i = 0; i < 4; i++) {
      int row = (((wm << 2) + i) << 4) + (quad << 2);
#pragma unroll
      for (int v = 0; v < 4; v++) {
        float val = acc[i][j][v] + bias;
        val = val / (1.0f + __expf(-1.702f * val));  // sigmoid-gelu (err ~0.02 -> ~1e-8 in output)
        rp[(row + v) * 136 + col] = f2bf(val);
      }
    }
  }
  __syncthreads();
  u16* hb = hid + (size_t)z * BP * HD + ((size_t)(bx << 7)) * HD + (by << 7);
#pragma unroll
  for (int it = 0; it < 4; it++) {
    int q = tid + (it << 8);
    int r = q >> 4, cc = (q & 15) << 3;
    *(uint4*)&hb[(size_t)r * HD + cc] = *(const uint4*)&rp[r * 136 + cc];
  }
}

// ---------------- GEMM2: y = (hid @ w2 + b2) * gate (bf16 out) ----------------
__global__ __launch_bounds__(256) void k_gemm2(const u16* __restrict__ hid,
                                               const u16* __restrict__ w2t,
                                               const float* __restrict__ b2,
                                               const float* __restrict__ dgate,
                                               u16* __restrict__ yb, int e0) {
  __shared__ __align__(16) char smem[35072];
  __shared__ float gates[128];
  short* As = (short*)smem;
  short* Bs = (short*)(smem + 8192);
  int tid = threadIdx.x;
  int bx = blockIdx.x, by = blockIdx.y, z = blockIdx.z;
  int e = e0 + z;
  if (tid < 128) gates[tid] = dgate[e * BP + (bx << 7) + tid];
  int f1 = tid, f2 = tid + 256;
  int m1 = ((f1 >> 6) << 4) | (f1 & 15), kq1 = (f1 >> 4) & 3;
  int m2 = ((f2 >> 6) << 4) | (f2 & 15), kq2 = (f2 >> 4) & 3;
  const u16* ab = hid + (size_t)(z * BP + (bx << 7)) * HD;
  const u16* a1p = ab + (size_t)m1 * HD + kq1 * 8;
  const u16* a2p = ab + (size_t)m2 * HD + kq2 * 8;
  const u16* bb = w2t + ((size_t)e * 384 + (by << 7)) * HD;
  const u16* bp1 = bb + (size_t)m1 * HD + kq1 * 8;
  const u16* bp2 = bb + (size_t)m2 * HD + kq2 * 8;
  int wv = tid >> 6, lane = tid & 63;
  int wm = wv & 1, wn = wv >> 1;
  f32x4 acc[4][4];
#pragma unroll
  for (int i = 0; i < 4; i++)
#pragma unroll
    for (int j = 0; j < 4; j++) acc[i][j] = (f32x4){0.f, 0.f, 0.f, 0.f};
  for (int kk = 0; kk < 48; kk++) {
    *(uint4*)&As[f1 * 8] = *(const uint4*)(a1p + kk * 32);
    *(uint4*)&As[f2 * 8] = *(const uint4*)(a2p + kk * 32);
    *(uint4*)&Bs[f1 * 8] = *(const uint4*)(bp1 + kk * 32);
    *(uint4*)&Bs[f2 * 8] = *(const uint4*)(bp2 + kk * 32);
    __syncthreads();
    bf16x8 af[4], bfr[4];
#pragma unroll
    for (int i = 0; i < 4; i++) af[i] = *(const bf16x8*)&As[((((wm << 2) + i) << 6) | lane) * 8];
#pragma unroll
    for (int j = 0; j < 4; j++) bfr[j] = *(const bf16x8*)&Bs[((((wn << 2) + j) << 6) | lane) * 8];
#pragma unroll
    for (int i = 0; i < 4; i++)
#pragma unroll
      for (int j = 0; j < 4; j++)
        acc[i][j] = __builtin_amdgcn_mfma_f32_16x16x32_bf16(af[i], bfr[j], acc[i][j], 0, 0, 0);
    __syncthreads();
  }
  int quad = lane >> 4, c15 = lane & 15;
  u16* rp = (u16*)smem;  // [128][136]
#pragma unroll
  for (int j = 0; j < 4; j++) {
    int col = (((wn << 2) + j) << 4) | c15;
    float bias = b2[e * 384 + (by << 7) + col];
#pragma unroll
    for (int i = 0; i < 4; i++) {
      int row = (((wm << 2) + i) << 4) + (quad << 2);
#pragma unroll
      for (int v = 0; v < 4; v++) {
        float val = (acc[i][j][v] + bias) * gates[row + v];
        rp[(row + v) * 136 + col] = f2bf(val);
      }
    }
  }
  __syncthreads();
  u16* ybb = yb + (size_t)(e * BP + (bx << 7)) * 384 + (by << 7);
#pragma unroll
  for (int it = 0; it < 4; it++) {
    int q = tid + (it << 8);
    int r = q >> 4, cc = (q & 15) << 3;
    *(uint4*)&ybb[(size_t)r * 384 + cc] = *(const uint4*)&rp[r * 136 + cc];
  }
}

// ---------------- combine: out = x + ls * (gathered y rows), NHWC->NCHW via LDS ----------------
__global__ __launch_bounds__(256) void k_final(const float* __restrict__ x,
                                               const u16* __restrict__ yb,
                                               const int* __restrict__ inv,
                                               const float* __restrict__ ls,
                                               float* __restrict__ out) {
  __shared__ float tile[32 * 385];
  __shared__ int sl[64];
  int nb = blockIdx.x;  // n*32 + y
  int n = nb >> 5, yy = nb & 31;
  int tid = threadIdx.x;
  int t0 = nb << 5;
  if (tid < 64) sl[tid] = inv[t0 * 2 + tid];
  for (int i = tid; i < 12320; i += 256) tile[i] = 0.0f;
  __syncthreads();
#pragma unroll
  for (int k = 0; k < 2; k++) {
    for (int idx = tid; idx < 12288; idx += 256) {
      int w = idx / 384, c = idx - w * 384;
      int s = sl[w * 2 + k];
      if (s >= 0) tile[w * 385 + c] += bf2f(yb[(size_t)s * 384 + c]);
    }
  }
  __syncthreads();
  for (int idx = tid; idx < 12288; idx += 256) {
    int c = idx >> 5, w = idx & 31;
    size_t o = ((((size_t)n * 384 + c) << 5) + yy) * 32 + w;
    out[o] = x[o] + ls[c] * tile[w * 385 + c];
  }
}

extern "C" void kernel_launch(void* const* d_in, const int* in_sizes, int n_in,
                              void* d_out, int out_size, void* d_ws, size_t ws_size,
                              hipStream_t stream) {
  (void)in_sizes; (void)n_in; (void)out_size; (void)ws_size;
  const float* x     = (const float*)d_in[0];
  const float* convw = (const float*)d_in[1];
  const float* convb = (const float*)d_in[2];
  const float* lng   = (const float*)d_in[3];
  const float* lnb   = (const float*)d_in[4];
  const float* gw    = (const float*)d_in[5];
  const float* w1    = (const float*)d_in[6];
  const float* b1    = (const float*)d_in[7];
  const float* w2    = (const float*)d_in[8];
  const float* b2    = (const float*)d_in[9];
  const float* ls    = (const float*)d_in[10];
  float* out = (float*)d_out;

  char* p = (char*)d_ws;
  size_t o = 0;
  auto alloc = [&](size_t b) { void* r = p + o; o += (b + 255) & ~(size_t)255; return r; };
  u16* xln    = (u16*)alloc((size_t)T_TOK * C_DIM * 2);          // 50.3 MB
  u16* w1t    = (u16*)alloc((size_t)8 * HD * C_DIM * 2);         // 9.4 MB
  u16* w2t    = (u16*)alloc((size_t)8 * HD * C_DIM * 2);         // 9.4 MB
  u16* hid    = (u16*)alloc((size_t)4 * BP * HD * 2);            // 162 MB (also aliased as conv out)
  u16* yb     = (u16*)alloc((size_t)8 * BP * 384 * 2);           // 81 MB
  u32* keysA  = (u32*)alloc((size_t)T_TOK * 4);
  u32* keysB  = (u32*)alloc((size_t)T_TOK * 4);
  u32* valsA  = (u32*)alloc((size_t)T_TOK * 4);
  u32* valsB  = (u32*)alloc((size_t)T_TOK * 4);
  u32* topi   = (u32*)alloc((size_t)T_TOK * 4);
  float* g1   = (float*)alloc((size_t)T_TOK * 4);
  float* g2   = (float*)alloc((size_t)T_TOK * 4);
  u32* hist   = (u32*)alloc((size_t)256 * 512 * 4);
  u32* ee     = (u32*)alloc((size_t)131072 * 4);
  u32* et     = (u32*)alloc((size_t)131072 * 4);
  float* eg   = (float*)alloc((size_t)131072 * 4);
  int* dtok   = (int*)alloc((size_t)8 * BP * 4);
  float* dgate= (float*)alloc((size_t)8 * BP * 4);
  int* inv    = (int*)alloc((size_t)T_TOK * 2 * 4);

  float* hconv = (float*)hid;  // alias: conv output consumed by k_ln before GEMM1 writes hid

  k_conv<<<24576, 256, 0, stream>>>(x, convw, convb, hconv);
  k_ln<<<2048, 256, 0, stream>>>(hconv, lng, lnb, xln);
  k_router<<<16384, 256, 0, stream>>>(xln, gw, keysA, valsA, topi, g1, g2);

  // stable radix sort by ~bits(priority): 4 x 8-bit passes, ends back in keysA/valsA
  u32 *ki = keysA, *vi = valsA, *ko = keysB, *vo = valsB;
  for (int pass = 0; pass < 4; pass++) {
    int shift = pass * 8;
    k_hist<<<256, 256, 0, stream>>>(ki, hist, shift);
    k_scan<<<1, 256, 0, stream>>>(hist, 65536);
    k_scatter<<<256, 256, 0, stream>>>(ki, vi, ko, vo, hist, shift);
    u32* t1 = ki; ki = ko; ko = t1;
    u32* t2 = vi; vi = vo; vo = t2;
  }
  k_entries<<<512, 256, 0, stream>>>(vi, topi, g1, g2, ee, et, eg);
  k_hist<<<512, 256, 0, stream>>>(ee, hist, 0);
  k_scan<<<1, 256, 0, stream>>>(hist, 131072);
  hipMemsetAsync(dtok, 0, (size_t)8 * BP * 4, stream);
  hipMemsetAsync(dgate, 0, (size_t)8 * BP * 4, stream);
  hipMemsetAsync(inv, 0xFF, (size_t)T_TOK * 2 * 4, stream);
  k_dispatch<<<512, 256, 0, stream>>>(ee, et, eg, hist, dtok, dgate, inv);

  k_transpose_bf16<<<dim3(48, 12, 8), dim3(32, 8), 0, stream>>>(w1, w1t, 384, 1536);
  k_transpose_bf16<<<dim3(12, 48, 8), dim3(32, 8), 0, stream>>>(w2, w2t, 1536, 384);

  for (int g = 0; g < 2; g++) {
    k_gemm1<<<dim3(103, 12, 4), 256, 0, stream>>>(xln, w1t, b1, dtok, hid, g * 4);
    k_gemm2<<<dim3(103, 3, 4), 256, 0, stream>>>(hid, w2t, b2, dgate, yb, g * 4);
  }
  k_final<<<2048, 256, 0, stream>>>(x, yb, inv, ls, out);
}

// Round 2
// 1206.797 us; speedup vs baseline: 1.4667x; 1.4667x over previous
//
#include <hip/hip_runtime.h>

// MoE ConvNeXt block: dwconv7x7 -> LN -> top2 router w/ capacity -> expert MLP (bf16 MFMA) -> combine
// Shapes: N=64 C=384 H=W=32 -> T=65536, E=8, K=2, Hd=1536, Be=13107, Bp=13184 (=103*128)
// R1: replaced single-block serial k_scan (5 x 191us!) with hierarchical scan
//     (row scan x256 blocks + digit scan), and O(tid)-serial local-rank loops in
//     scatter/dispatch with ballot-based ranking.

typedef unsigned int u32;
typedef unsigned long long u64;
typedef unsigned short u16;
typedef __attribute__((ext_vector_type(8))) __bf16 bf16x8;
typedef __attribute__((ext_vector_type(4))) float f32x4;

#define T_TOK 65536
#define C_DIM 384
#define HD 1536
#define BE 13107
#define BP 13184

__device__ __forceinline__ u16 f2bf(float f) {
  u32 u = __float_as_uint(f);
  u32 r = (u + 0x7FFFu + ((u >> 16) & 1u)) >> 16;
  return (u16)r;
}
__device__ __forceinline__ float bf2f(u16 b) { return __uint_as_float(((u32)b) << 16); }

// ---------------- depthwise conv 7x7 (one (n,c) plane per block) ----------------
__global__ __launch_bounds__(256) void k_conv(const float* __restrict__ x,
                                              const float* __restrict__ cw,
                                              const float* __restrict__ cb,
                                              float* __restrict__ hconv) {
  __shared__ float xp[38 * 40];  // padded plane: rows y+3 in [0,38), cols x+3 in [0,40)
  __shared__ float cwl[49];
  int b = blockIdx.x;            // n*384 + c
  int c = b % 384;
  int tid = threadIdx.x;
  for (int i = tid; i < 1520; i += 256) xp[i] = 0.0f;
  if (tid < 49) cwl[tid] = cw[tid * 384 + c];
  __syncthreads();
  const float* xsrc = x + (size_t)b * 1024;
  {
    float4 v = *(const float4*)&xsrc[tid * 4];
    int yy = tid >> 3, xx = (tid & 7) * 4;
    float* d = &xp[(yy + 3) * 40 + xx + 3];
    d[0] = v.x; d[1] = v.y; d[2] = v.z; d[3] = v.w;
  }
  __syncthreads();
  int ty = tid >> 3, w0 = (tid & 7) * 4;
  float bias = cb[c];
  float o0 = bias, o1 = bias, o2 = bias, o3 = bias;
#pragma unroll
  for (int dy = 0; dy < 7; dy++) {
    const float* row = &xp[(ty + dy) * 40 + w0];
    float4 A = *(const float4*)row;
    float4 B = *(const float4*)(row + 4);
    float4 Cc = *(const float4*)(row + 8);
    float v0 = A.x, v1 = A.y, v2 = A.z, v3 = A.w;
    float v4 = B.x, v5 = B.y, v6 = B.z, v7 = B.w;
    float v8 = Cc.x, v9 = Cc.y;
    const float* wrow = &cwl[dy * 7];
    float wt;
    wt = wrow[0]; o0 += wt * v0; o1 += wt * v1; o2 += wt * v2; o3 += wt * v3;
    wt = wrow[1]; o0 += wt * v1; o1 += wt * v2; o2 += wt * v3; o3 += wt * v4;
    wt = wrow[2]; o0 += wt * v2; o1 += wt * v3; o2 += wt * v4; o3 += wt * v5;
    wt = wrow[3]; o0 += wt * v3; o1 += wt * v4; o2 += wt * v5; o3 += wt * v6;
    wt = wrow[4]; o0 += wt * v4; o1 += wt * v5; o2 += wt * v6; o3 += wt * v7;
    wt = wrow[5]; o0 += wt * v5; o1 += wt * v6; o2 += wt * v7; o3 += wt * v8;
    wt = wrow[6]; o0 += wt * v6; o1 += wt * v7; o2 += wt * v8; o3 += wt * v9;
  }
  float4 ov = {o0, o1, o2, o3};
  *(float4*)&hconv[(size_t)b * 1024 + ty * 32 + w0] = ov;
}

// ---------------- LayerNorm (over C) + bf16 cast; block = one (n,y) row of 32 tokens ----------------
__global__ __launch_bounds__(256) void k_ln(const float* __restrict__ hconv,
                                            const float* __restrict__ lng,
                                            const float* __restrict__ lnb,
                                            u16* __restrict__ xln) {
  __shared__ float tile[384 * 33];  // [c][w], stride 33 to break bank conflicts
  int nb = blockIdx.x;              // n*32 + y
  int n = nb >> 5, y = nb & 31;
  int tid = threadIdx.x;
  const float* src = hconv + (size_t)n * 384 * 1024 + (y << 5);
  for (int i = tid; i < 12288; i += 256) {
    int c = i >> 5, w = i & 31;
    tile[c * 33 + w] = src[(size_t)c * 1024 + w];
  }
  __syncthreads();
  int wv = tid >> 6, lane = tid & 63;
  for (int w = wv; w < 32; w += 4) {
    float v[6];
    float s = 0.f, s2 = 0.f;
#pragma unroll
    for (int k = 0; k < 6; k++) {
      float t = tile[(lane + (k << 6)) * 33 + w];
      v[k] = t; s += t; s2 += t * t;
    }
#pragma unroll
    for (int off = 32; off > 0; off >>= 1) {
      s += __shfl_xor(s, off, 64);
      s2 += __shfl_xor(s2, off, 64);
    }
    float mu = s * (1.0f / 384.0f);
    float var = s2 * (1.0f / 384.0f) - mu * mu;
    float r = rsqrtf(var + 1e-6f);
    size_t t0 = ((size_t)nb << 5) + w;  // token index
#pragma unroll
    for (int k = 0; k < 6; k++) {
      int c = lane + (k << 6);
      float o = (v[k] - mu) * r * lng[c] + lnb[c];
      xln[t0 * 384 + c] = f2bf(o);
    }
  }
}

// ---------------- router: logits(8), softmax max -> priority key, top2 + gates ----------------
__global__ __launch_bounds__(256) void k_router(const u16* __restrict__ xln,
                                                const float* __restrict__ gw,
                                                u32* __restrict__ keys, u32* __restrict__ vals,
                                                u32* __restrict__ topi,
                                                float* __restrict__ g1, float* __restrict__ g2) {
  __shared__ float gwl[8 * 384];
  int tid = threadIdx.x;
  for (int i = tid; i < 3072; i += 256) gwl[i] = gw[i];
  __syncthreads();
  int wv = tid >> 6, lane = tid & 63;
  int t = (blockIdx.x << 2) + wv;
  float acc[8] = {0, 0, 0, 0, 0, 0, 0, 0};
#pragma unroll
  for (int k = 0; k < 6; k++) {
    int c = lane + (k << 6);
    float xv = bf2f(xln[(size_t)t * 384 + c]);
#pragma unroll
    for (int e = 0; e < 8; e++) acc[e] += xv * gwl[e * 384 + c];
  }
#pragma unroll
  for (int off = 32; off > 0; off >>= 1) {
#pragma unroll
    for (int e = 0; e < 8; e++) acc[e] += __shfl_xor(acc[e], off, 64);
  }
  if (lane == 0) {
    float v1 = -1e30f, v2 = -1e30f;
    int e1 = 0, e2 = 0;
#pragma unroll
    for (int e = 0; e < 8; e++) {
      float l = acc[e];
      if (l > v1) { v2 = v1; e2 = e1; v1 = l; e1 = e; }
      else if (l > v2) { v2 = l; e2 = e; }
    }
    float sum = 0.f;
#pragma unroll
    for (int e = 0; e < 8; e++) sum += __expf(acc[e] - v1);
    float p = 1.0f / sum;               // = max softmax prob
    float ew = __expf(v2 - v1);
    float w1 = 1.0f / (1.0f + ew);
    keys[t] = ~__float_as_uint(p);      // ascending sort == descending priority, stable
    vals[t] = (u32)t;
    topi[t] = (u32)e1 | ((u32)e2 << 8);
    g1[t] = w1;
    g2[t] = ew * w1;
  }
}

// ---------------- stable counting-sort machinery (8-bit digit) ----------------
__global__ __launch_bounds__(256) void k_hist(const u32* __restrict__ keys,
                                              u32* __restrict__ hist, int shift) {
  __shared__ u32 h[256];
  int tid = threadIdx.x;
  h[tid] = 0;
  __syncthreads();
  u32 key = keys[((size_t)blockIdx.x << 8) + tid];
  atomicAdd(&h[(key >> shift) & 255u], 1u);
  __syncthreads();
  hist[(size_t)tid * gridDim.x + blockIdx.x] = h[tid];
}

// row-local exclusive scan: one block per digit row of `nb` per-block counts.
// data[d*nb + i] -> exclusive prefix within row d; totals[d] = row sum.
__global__ __launch_bounds__(256) void k_scan_rows(u32* __restrict__ data,
                                                   u32* __restrict__ totals, int nb) {
  __shared__ u32 ws[256];
  int d = blockIdx.x, tid = threadIdx.x;
  int seg = nb >> 8;  // 1 or 2
  u32 base = (u32)d * nb + tid * seg;
  u32 v[2] = {0, 0};
  u32 s = 0;
  for (int i = 0; i < seg; i++) { v[i] = data[base + i]; s += v[i]; }
  ws[tid] = s;
  __syncthreads();
  for (int dd = 1; dd < 256; dd <<= 1) {
    u32 t = (tid >= dd) ? ws[tid - dd] : 0u;
    __syncthreads();
    ws[tid] += t;
    __syncthreads();
  }
  if (tid == 255) totals[d] = ws[255];
  u32 run = (tid > 0) ? ws[tid - 1] : 0u;
  for (int i = 0; i < seg; i++) {
    u32 tmp = v[i];
    data[base + i] = run;
    run += tmp;
  }
}

// exclusive scan of the 256 digit totals -> dbase
__global__ __launch_bounds__(256) void k_scan_digits(const u32* __restrict__ totals,
                                                     u32* __restrict__ dbase) {
  __shared__ u32 ws[256];
  int tid = threadIdx.x;
  ws[tid] = totals[tid];
  __syncthreads();
  for (int dd = 1; dd < 256; dd <<= 1) {
    u32 t = (tid >= dd) ? ws[tid - dd] : 0u;
    __syncthreads();
    ws[tid] += t;
    __syncthreads();
  }
  dbase[tid] = (tid > 0) ? ws[tid - 1] : 0u;
}

// stable scatter with ballot-based local rank (4 waves x 256 digits)
__global__ __launch_bounds__(256) void k_scatter(const u32* __restrict__ kin,
                                                 const u32* __restrict__ vin,
                                                 u32* __restrict__ kout, u32* __restrict__ vout,
                                                 const u32* __restrict__ scanned,
                                                 const u32* __restrict__ dbase, int shift) {
  __shared__ u32 cnt[4 * 256];
  int tid = threadIdx.x;
  int w = tid >> 6, l = tid & 63;
  int g = (blockIdx.x << 8) + tid;
  u32 key = kin[g], val = vin[g];
  u32 d = (key >> shift) & 255u;
  for (int i = tid; i < 1024; i += 256) cnt[i] = 0u;
  __syncthreads();
  u64 match = ~0ull;
#pragma unroll
  for (int b = 0; b < 8; b++) {
    int bit = (d >> b) & 1;
    u64 bal = __ballot(bit);
    match &= bit ? bal : ~bal;
  }
  u32 rw = __popcll(match & ((1ull << l) - 1ull));
  if (rw == 0) cnt[(w << 8) + d] = (u32)__popcll(match);
  __syncthreads();
  u32 pre = 0;
  for (int w2 = 0; w2 < w; w2++) pre += cnt[(w2 << 8) + d];
  u32 pos = dbase[d] + scanned[(size_t)d * gridDim.x + blockIdx.x] + pre + rw;
  kout[pos] = key;
  vout[pos] = val;
}

// build k-major entry list over priority-sorted tokens
__global__ __launch_bounds__(256) void k_entries(const u32* __restrict__ order,
                                                 const u32* __restrict__ topi,
                                                 const float* __restrict__ g1,
                                                 const float* __restrict__ g2,
                                                 u32* __restrict__ ee, u32* __restrict__ et,
                                                 float* __restrict__ eg) {
  int m = (blockIdx.x << 8) + threadIdx.x;
  int i = m & 65535, k = m >> 16;
  u32 tok = order[i];
  u32 pk = topi[tok];
  ee[m] = k ? ((pk >> 8) & 255u) : (pk & 255u);
  et[m] = tok;
  eg[m] = k ? g2[tok] : g1[tok];
}

// stable counting sort by expert + capacity truncation -> dispatch tables + inverse map
// scanned rows are expert-row-local, so the row-local prefix IS the within-expert position.
__global__ __launch_bounds__(256) void k_dispatch(const u32* __restrict__ ee,
                                                  const u32* __restrict__ et,
                                                  const float* __restrict__ eg,
                                                  const u32* __restrict__ scanned,
                                                  int* __restrict__ dtok, float* __restrict__ dgate,
                                                  int* __restrict__ inv) {
  __shared__ u32 cnt[4 * 8];
  int tid = threadIdx.x;
  int w = tid >> 6, l = tid & 63;
  int m = (blockIdx.x << 8) + tid;
  u32 e = ee[m];
  if (tid < 32) cnt[tid] = 0u;
  __syncthreads();
  u64 match = ~0ull;
#pragma unroll
  for (int b = 0; b < 3; b++) {
    int bit = (e >> b) & 1;
    u64 bal = __ballot(bit);
    match &= bit ? bal : ~bal;
  }
  u32 rw = __popcll(match & ((1ull << l) - 1ull));
  if (rw == 0) cnt[(w << 3) + e] = (u32)__popcll(match);
  __syncthreads();
  u32 pre = 0;
  for (int w2 = 0; w2 < w; w2++) pre += cnt[(w2 << 3) + e];
  u32 pos = scanned[(size_t)e * gridDim.x + blockIdx.x] + pre + rw;
  if (pos < (u32)BE) {
    int slot = (int)e * BP + (int)pos;
    dtok[slot] = (int)et[m];
    dgate[slot] = eg[m];
    inv[et[m] * 2 + (m >> 16)] = slot;
  }
}

// ---------------- fp32 -> bf16 transposed weight prep: in [E][R][S] -> out [E][S][R] ----------------
__global__ __launch_bounds__(256) void k_transpose_bf16(const float* __restrict__ in,
                                                        u16* __restrict__ out, int R, int S) {
  __shared__ float t[32][33];
  int e = blockIdx.z;
  const float* ip = in + (size_t)e * R * S;
  u16* op = out + (size_t)e * R * S;
  int s0 = blockIdx.x << 5, r0 = blockIdx.y << 5;
  int tx = threadIdx.x, ty = threadIdx.y;
#pragma unroll
  for (int i = 0; i < 4; i++) {
    int r = r0 + ty + (i << 3);
    t[ty + (i << 3)][tx] = ip[(size_t)r * S + s0 + tx];
  }
  __syncthreads();
#pragma unroll
  for (int i = 0; i < 4; i++) {
    int s = s0 + ty + (i << 3);
    op[(size_t)s * R + r0 + tx] = f2bf(t[tx][ty + (i << 3)]);
  }
}

// ---------------- GEMM1: hid = gelu(gather(xln) @ w1 + b1), 128x128x32 MFMA tiles ----------------
__global__ __launch_bounds__(256) void k_gemm1(const u16* __restrict__ xln,
                                               const u16* __restrict__ w1t,
                                               const float* __restrict__ b1,
                                               const int* __restrict__ dtok,
                                               u16* __restrict__ hid, int e0) {
  __shared__ __align__(16) char smem[35072];  // staging 16KB; reused as 128x136 bf16 repack
  short* As = (short*)smem;
  short* Bs = (short*)(smem + 8192);
  int tid = threadIdx.x;
  int bx = blockIdx.x, by = blockIdx.y, z = blockIdx.z;
  int e = e0 + z;
  int f1 = tid, f2 = tid + 256;
  int m1 = ((f1 >> 6) << 4) | (f1 & 15), kq1 = (f1 >> 4) & 3;
  int m2 = ((f2 >> 6) << 4) | (f2 & 15), kq2 = (f2 >> 4) & 3;
  int dbase = e * BP + (bx << 7);
  int tokA1 = dtok[dbase + m1];
  int tokA2 = dtok[dbase + m2];
  const u16* a1p = xln + (size_t)tokA1 * 384 + kq1 * 8;
  const u16* a2p = xln + (size_t)tokA2 * 384 + kq2 * 8;
  const u16* bb = w1t + ((size_t)e * HD + (by << 7)) * 384;
  const u16* bp1 = bb + (size_t)m1 * 384 + kq1 * 8;
  const u16* bp2 = bb + (size_t)m2 * 384 + kq2 * 8;
  int wv = tid >> 6, lane = tid & 63;
  int wm = wv & 1, wn = wv >> 1;
  f32x4 acc[4][4];
#pragma unroll
  for (int i = 0; i < 4; i++)
#pragma unroll
    for (int j = 0; j < 4; j++) acc[i][j] = (f32x4){0.f, 0.f, 0.f, 0.f};
  for (int kk = 0; kk < 12; kk++) {
    *(uint4*)&As[f1 * 8] = *(const uint4*)(a1p + kk * 32);
    *(uint4*)&As[f2 * 8] = *(const uint4*)(a2p + kk * 32);
    *(uint4*)&Bs[f1 * 8] = *(const uint4*)(bp1 + kk * 32);
    *(uint4*)&Bs[f2 * 8] = *(const uint4*)(bp2 + kk * 32);
    __syncthreads();
    bf16x8 af[4], bfr[4];
#pragma unroll
    for (int i = 0; i < 4; i++) af[i] = *(const bf16x8*)&As[((((wm << 2) + i) << 6) | lane) * 8];
#pragma unroll
    for (int j = 0; j < 4; j++) bfr[j] = *(const bf16x8*)&Bs[((((wn << 2) + j) << 6) | lane) * 8];
#pragma unroll
    for (int i = 0; i < 4; i++)
#pragma unroll
      for (int j = 0; j < 4; j++)
        acc[i][j] = __builtin_amdgcn_mfma_f32_16x16x32_bf16(af[i], bfr[j], acc[i][j], 0, 0, 0);
    __syncthreads();
  }
  int quad = lane >> 4, c15 = lane & 15;
  u16* rp = (u16*)smem;  // [128][136]
#pragma unroll
  for (int j = 0; j < 4; j++) {
    int col = (((wn << 2) + j) << 4) | c15;
    float bias = b1[e * HD + (by << 7) + col];
#pragma unroll
    for (int i = 0; i < 4; i++) {
      int row = (((wm << 2) + i) << 4) + (quad << 2);
#pragma unroll
      for (int v = 0; v < 4; v++) {
        float val = acc[i][j][v] + bias;
        val = val / (1.0f + __expf(-1.702f * val));  // sigmoid-gelu (err ~0.02 -> ~1e-8 in output)
        rp[(row + v) * 136 + col] = f2bf(val);
      }
    }
  }
  __syncthreads();
  u16* hb = hid + (size_t)z * BP * HD + ((size_t)(bx << 7)) * HD + (by << 7);
#pragma unroll
  for (int it = 0; it < 4; it++) {
    int q = tid + (it << 8);
    int r = q >> 4, cc = (q & 15) << 3;
    *(uint4*)&hb[(size_t)r * HD + cc] = *(const uint4*)&rp[r * 136 + cc];
  }
}

// ---------------- GEMM2: y = (hid @ w2 + b2) * gate (bf16 out) ----------------
__global__ __launch_bounds__(256) void k_gemm2(const u16* __restrict__ hid,
                                               const u16* __restrict__ w2t,
                                               const float* __restrict__ b2,
                                               const float* __restrict__ dgate,
                                               u16* __restrict__ yb, int e0) {
  __shared__ __align__(16) char smem[35072];
  __shared__ float gates[128];
  short* As = (short*)smem;
  short* Bs = (short*)(smem + 8192);
  int tid = threadIdx.x;
  int bx = blockIdx.x, by = blockIdx.y, z = blockIdx.z;
  int e = e0 + z;
  if (tid < 128) gates[tid] = dgate[e * BP + (bx << 7) + tid];
  int f1 = tid, f2 = tid + 256;
  int m1 = ((f1 >> 6) << 4) | (f1 & 15), kq1 = (f1 >> 4) & 3;
  int m2 = ((f2 >> 6) << 4) | (f2 & 15), kq2 = (f2 >> 4) & 3;
  const u16* ab = hid + (size_t)(z * BP + (bx << 7)) * HD;
  const u16* a1p = ab + (size_t)m1 * HD + kq1 * 8;
  const u16* a2p = ab + (size_t)m2 * HD + kq2 * 8;
  const u16* bb = w2t + ((size_t)e * 384 + (by << 7)) * HD;
  const u16* bp1 = bb + (size_t)m1 * HD + kq1 * 8;
  const u16* bp2 = bb + (size_t)m2 * HD + kq2 * 8;
  int wv = tid >> 6, lane = tid & 63;
  int wm = wv & 1, wn = wv >> 1;
  f32x4 acc[4][4];
#pragma unroll
  for (int i = 0; i < 4; i++)
#pragma unroll
    for (int j = 0; j < 4; j++) acc[i][j] = (f32x4){0.f, 0.f, 0.f, 0.f};
  for (int kk = 0; kk < 48; kk++) {
    *(uint4*)&As[f1 * 8] = *(const uint4*)(a1p + kk * 32);
    *(uint4*)&As[f2 * 8] = *(const uint4*)(a2p + kk * 32);
    *(uint4*)&Bs[f1 * 8] = *(const uint4*)(bp1 + kk * 32);
    *(uint4*)&Bs[f2 * 8] = *(const uint4*)(bp2 + kk * 32);
    __syncthreads();
    bf16x8 af[4], bfr[4];
#pragma unroll
    for (int i = 0; i < 4; i++) af[i] = *(const bf16x8*)&As[((((wm << 2) + i) << 6) | lane) * 8];
#pragma unroll
    for (int j = 0; j < 4; j++) bfr[j] = *(const bf16x8*)&Bs[((((wn << 2) + j) << 6) | lane) * 8];
#pragma unroll
    for (int i = 0; i < 4; i++)
#pragma unroll
      for (int j = 0; j < 4; j++)
        acc[i][j] = __builtin_amdgcn_mfma_f32_16x16x32_bf16(af[i], bfr[j], acc[i][j], 0, 0, 0);
    __syncthreads();
  }
  int quad = lane >> 4, c15 = lane & 15;
  u16* rp = (u16*)smem;  // [128][136]
#pragma unroll
  for (int j = 0; j < 4; j++) {
    int col = (((wn << 2) + j) << 4) | c15;
    float bias = b2[e * 384 + (by << 7) + col];
#pragma unroll
    for (int i = 0; i < 4; i++) {
      int row = (((wm << 2) + i) << 4) + (quad << 2);
#pragma unroll
      for (int v = 0; v < 4; v++) {
        float val = (acc[i][j][v] + bias) * gates[row + v];
        rp[(row + v) * 136 + col] = f2bf(val);
      }
    }
  }
  __syncthreads();
  u16* ybb = yb + (size_t)(e * BP + (bx << 7)) * 384 + (by << 7);
#pragma unroll
  for (int it = 0; it < 4; it++) {
    int q = tid + (it << 8);
    int r = q >> 4, cc = (q & 15) << 3;
    *(uint4*)&ybb[(size_t)r * 384 + cc] = *(const uint4*)&rp[r * 136 + cc];
  }
}

// ---------------- combine: out = x + ls * (gathered y rows), NHWC->NCHW via LDS ----------------
__global__ __launch_bounds__(256) void k_final(const float* __restrict__ x,
                                               const u16* __restrict__ yb,
                                               const int* __restrict__ inv,
                                               const float* __restrict__ ls,
                                               float* __restrict__ out) {
  __shared__ float tile[32 * 385];
  __shared__ int sl[64];
  int nb = blockIdx.x;  // n*32 + y
  int n = nb >> 5, yy = nb & 31;
  int tid = threadIdx.x;
  int t0 = nb << 5;
  if (tid < 64) sl[tid] = inv[t0 * 2 + tid];
  for (int i = tid; i < 12320; i += 256) tile[i] = 0.0f;
  __syncthreads();
#pragma unroll
  for (int k = 0; k < 2; k++) {
    for (int idx = tid; idx < 12288; idx += 256) {
      int w = idx / 384, c = idx - w * 384;
      int s = sl[w * 2 + k];
      if (s >= 0) tile[w * 385 + c] += bf2f(yb[(size_t)s * 384 + c]);
    }
  }
  __syncthreads();
  for (int idx = tid; idx < 12288; idx += 256) {
    int c = idx >> 5, w = idx & 31;
    size_t o = ((((size_t)n * 384 + c) << 5) + yy) * 32 + w;
    out[o] = x[o] + ls[c] * tile[w * 385 + c];
  }
}

extern "C" void kernel_launch(void* const* d_in, const int* in_sizes, int n_in,
                              void* d_out, int out_size, void* d_ws, size_t ws_size,
                              hipStream_t stream) {
  (void)in_sizes; (void)n_in; (void)out_size; (void)ws_size;
  const float* x     = (const float*)d_in[0];
  const float* convw = (const float*)d_in[1];
  const float* convb = (const float*)d_in[2];
  const float* lng   = (const float*)d_in[3];
  const float* lnb   = (const float*)d_in[4];
  const float* gw    = (const float*)d_in[5];
  const float* w1    = (const float*)d_in[6];
  const float* b1    = (const float*)d_in[7];
  const float* w2    = (const float*)d_in[8];
  const float* b2    = (const float*)d_in[9];
  const float* ls    = (const float*)d_in[10];
  float* out = (float*)d_out;

  char* p = (char*)d_ws;
  size_t o = 0;
  auto alloc = [&](size_t b) { void* r = p + o; o += (b + 255) & ~(size_t)255; return r; };
  u16* xln    = (u16*)alloc((size_t)T_TOK * C_DIM * 2);          // 50.3 MB
  u16* w1t    = (u16*)alloc((size_t)8 * HD * C_DIM * 2);         // 9.4 MB
  u16* w2t    = (u16*)alloc((size_t)8 * HD * C_DIM * 2);         // 9.4 MB
  u16* hid    = (u16*)alloc((size_t)4 * BP * HD * 2);            // 162 MB (also aliased as conv out)
  u16* yb     = (u16*)alloc((size_t)8 * BP * 384 * 2);           // 81 MB
  u32* keysA  = (u32*)alloc((size_t)T_TOK * 4);
  u32* keysB  = (u32*)alloc((size_t)T_TOK * 4);
  u32* valsA  = (u32*)alloc((size_t)T_TOK * 4);
  u32* valsB  = (u32*)alloc((size_t)T_TOK * 4);
  u32* topi   = (u32*)alloc((size_t)T_TOK * 4);
  float* g1   = (float*)alloc((size_t)T_TOK * 4);
  float* g2   = (float*)alloc((size_t)T_TOK * 4);
  u32* hist   = (u32*)alloc((size_t)256 * 512 * 4);
  u32* totals = (u32*)alloc((size_t)256 * 4);
  u32* dbase  = (u32*)alloc((size_t)256 * 4);
  u32* ee     = (u32*)alloc((size_t)131072 * 4);
  u32* et     = (u32*)alloc((size_t)131072 * 4);
  float* eg   = (float*)alloc((size_t)131072 * 4);
  int* dtok   = (int*)alloc((size_t)8 * BP * 4);
  float* dgate= (float*)alloc((size_t)8 * BP * 4);
  int* inv    = (int*)alloc((size_t)T_TOK * 2 * 4);

  float* hconv = (float*)hid;  // alias: conv output consumed by k_ln before GEMM1 writes hid

  k_conv<<<24576, 256, 0, stream>>>(x, convw, convb, hconv);
  k_ln<<<2048, 256, 0, stream>>>(hconv, lng, lnb, xln);
  k_router<<<16384, 256, 0, stream>>>(xln, gw, keysA, valsA, topi, g1, g2);

  // stable radix sort by ~bits(priority): 4 x 8-bit passes, ends back in keysA/valsA
  u32 *ki = keysA, *vi = valsA, *ko = keysB, *vo = valsB;
  for (int pass = 0; pass < 4; pass++) {
    int shift = pass * 8;
    k_hist<<<256, 256, 0, stream>>>(ki, hist, shift);
    k_scan_rows<<<256, 256, 0, stream>>>(hist, totals, 256);
    k_scan_digits<<<1, 256, 0, stream>>>(totals, dbase);
    k_scatter<<<256, 256, 0, stream>>>(ki, vi, ko, vo, hist, dbase, shift);
    u32* t1 = ki; ki = ko; ko = t1;
    u32* t2 = vi; vi = vo; vo = t2;
  }
  k_entries<<<512, 256, 0, stream>>>(vi, topi, g1, g2, ee, et, eg);
  k_hist<<<512, 256, 0, stream>>>(ee, hist, 0);
  k_scan_rows<<<256, 256, 0, stream>>>(hist, totals, 512);
  hipMemsetAsync(dtok, 0, (size_t)8 * BP * 4, stream);
  hipMemsetAsync(dgate, 0, (size_t)8 * BP * 4, stream);
  hipMemsetAsync(inv, 0xFF, (size_t)T_TOK * 2 * 4, stream);
  k_dispatch<<<512, 256, 0, stream>>>(ee, et, eg, hist, dtok, dgate, inv);

  k_transpose_bf16<<<dim3(48, 12, 8), dim3(32, 8), 0, stream>>>(w1, w1t, 384, 1536);
  k_transpose_bf16<<<dim3(12, 48, 8), dim3(32, 8), 0, stream>>>(w2, w2t, 1536, 384);

  for (int g = 0; g < 2; g++) {
    k_gemm1<<<dim3(103, 12, 4), 256, 0, stream>>>(xln, w1t, b1, dtok, hid, g * 4);
    k_gemm2<<<dim3(103, 3, 4), 256, 0, stream>>>(hid, w2t, b2, dgate, yb, g * 4);
  }
  k_final<<<2048, 256, 0, stream>>>(x, yb, inv, ls, out);
}

// Round 3
// 1063.812 us; speedup vs baseline: 1.6639x; 1.1344x over previous
//
#include <hip/hip_runtime.h>

// MoE ConvNeXt block: dwconv7x7 -> LN -> top2 router w/ capacity -> expert MLP (bf16 MFMA) -> combine
// Shapes: N=64 C=384 H=W=32 -> T=65536, E=8, K=2, Hd=1536, Be=13107, Bp=13184 (=103*128)
// R1: hierarchical scan + ballot ranking (1770 -> 1207 us)
// R2: GEMM staging via __builtin_amdgcn_global_load_lds width=16 (m93->m97 step, kills the
//     VGPR round-trip that had VALUBusy=40%/MfmaUtil=14.5%); k_final vectorized gather.

typedef unsigned int u32;
typedef unsigned long long u64;
typedef unsigned short u16;
typedef __attribute__((ext_vector_type(8))) __bf16 bf16x8;
typedef __attribute__((ext_vector_type(4))) float f32x4;

#define T_TOK 65536
#define C_DIM 384
#define HD 1536
#define BE 13107
#define BP 13184

__device__ __forceinline__ u16 f2bf(float f) {
  u32 u = __float_as_uint(f);
  u32 r = (u + 0x7FFFu + ((u >> 16) & 1u)) >> 16;
  return (u16)r;
}
__device__ __forceinline__ float bf2f(u16 b) { return __uint_as_float(((u32)b) << 16); }

// async HBM->LDS DMA, 16B per lane; LDS dest must be wave-uniform-base + lane*16 (ours is).
__device__ __forceinline__ void gl16(const void* g, void* l) {
  __builtin_amdgcn_global_load_lds((const __attribute__((address_space(1))) void*)g,
                                   (__attribute__((address_space(3))) void*)l, 16, 0, 0);
}

// ---------------- depthwise conv 7x7 (one (n,c) plane per block) ----------------
__global__ __launch_bounds__(256) void k_conv(const float* __restrict__ x,
                                              const float* __restrict__ cw,
                                              const float* __restrict__ cb,
                                              float* __restrict__ hconv) {
  __shared__ float xp[38 * 40];  // padded plane: rows y+3 in [0,38), cols x+3 in [0,40)
  __shared__ float cwl[49];
  int b = blockIdx.x;            // n*384 + c
  int c = b % 384;
  int tid = threadIdx.x;
  for (int i = tid; i < 1520; i += 256) xp[i] = 0.0f;
  if (tid < 49) cwl[tid] = cw[tid * 384 + c];
  __syncthreads();
  const float* xsrc = x + (size_t)b * 1024;
  {
    float4 v = *(const float4*)&xsrc[tid * 4];
    int yy = tid >> 3, xx = (tid & 7) * 4;
    float* d = &xp[(yy + 3) * 40 + xx + 3];
    d[0] = v.x; d[1] = v.y; d[2] = v.z; d[3] = v.w;
  }
  __syncthreads();
  int ty = tid >> 3, w0 = (tid & 7) * 4;
  float bias = cb[c];
  float o0 = bias, o1 = bias, o2 = bias, o3 = bias;
#pragma unroll
  for (int dy = 0; dy < 7; dy++) {
    const float* row = &xp[(ty + dy) * 40 + w0];
    float4 A = *(const float4*)row;
    float4 B = *(const float4*)(row + 4);
    float4 Cc = *(const float4*)(row + 8);
    float v0 = A.x, v1 = A.y, v2 = A.z, v3 = A.w;
    float v4 = B.x, v5 = B.y, v6 = B.z, v7 = B.w;
    float v8 = Cc.x, v9 = Cc.y;
    const float* wrow = &cwl[dy * 7];
    float wt;
    wt = wrow[0]; o0 += wt * v0; o1 += wt * v1; o2 += wt * v2; o3 += wt * v3;
    wt = wrow[1]; o0 += wt * v1; o1 += wt * v2; o2 += wt * v3; o3 += wt * v4;
    wt = wrow[2]; o0 += wt * v2; o1 += wt * v3; o2 += wt * v4; o3 += wt * v5;
    wt = wrow[3]; o0 += wt * v3; o1 += wt * v4; o2 += wt * v5; o3 += wt * v6;
    wt = wrow[4]; o0 += wt * v4; o1 += wt * v5; o2 += wt * v6; o3 += wt * v7;
    wt = wrow[5]; o0 += wt * v5; o1 += wt * v6; o2 += wt * v7; o3 += wt * v8;
    wt = wrow[6]; o0 += wt * v6; o1 += wt * v7; o2 += wt * v8; o3 += wt * v9;
  }
  float4 ov = {o0, o1, o2, o3};
  *(float4*)&hconv[(size_t)b * 1024 + ty * 32 + w0] = ov;
}

// ---------------- LayerNorm (over C) + bf16 cast; block = one (n,y) row of 32 tokens ----------------
__global__ __launch_bounds__(256) void k_ln(const float* __restrict__ hconv,
                                            const float* __restrict__ lng,
                                            const float* __restrict__ lnb,
                                            u16* __restrict__ xln) {
  __shared__ float tile[384 * 33];  // [c][w], stride 33 to break bank conflicts
  int nb = blockIdx.x;              // n*32 + y
  int n = nb >> 5, y = nb & 31;
  int tid = threadIdx.x;
  const float* src = hconv + (size_t)n * 384 * 1024 + (y << 5);
  for (int i = tid; i < 12288; i += 256) {
    int c = i >> 5, w = i & 31;
    tile[c * 33 + w] = src[(size_t)c * 1024 + w];
  }
  __syncthreads();
  int wv = tid >> 6, lane = tid & 63;
  for (int w = wv; w < 32; w += 4) {
    float v[6];
    float s = 0.f, s2 = 0.f;
#pragma unroll
    for (int k = 0; k < 6; k++) {
      float t = tile[(lane + (k << 6)) * 33 + w];
      v[k] = t; s += t; s2 += t * t;
    }
#pragma unroll
    for (int off = 32; off > 0; off >>= 1) {
      s += __shfl_xor(s, off, 64);
      s2 += __shfl_xor(s2, off, 64);
    }
    float mu = s * (1.0f / 384.0f);
    float var = s2 * (1.0f / 384.0f) - mu * mu;
    float r = rsqrtf(var + 1e-6f);
    size_t t0 = ((size_t)nb << 5) + w;  // token index
#pragma unroll
    for (int k = 0; k < 6; k++) {
      int c = lane + (k << 6);
      float o = (v[k] - mu) * r * lng[c] + lnb[c];
      xln[t0 * 384 + c] = f2bf(o);
    }
  }
}

// ---------------- router: logits(8), softmax max -> priority key, top2 + gates ----------------
__global__ __launch_bounds__(256) void k_router(const u16* __restrict__ xln,
                                                const float* __restrict__ gw,
                                                u32* __restrict__ keys, u32* __restrict__ vals,
                                                u32* __restrict__ topi,
                                                float* __restrict__ g1, float* __restrict__ g2) {
  __shared__ float gwl[8 * 384];
  int tid = threadIdx.x;
  for (int i = tid; i < 3072; i += 256) gwl[i] = gw[i];
  __syncthreads();
  int wv = tid >> 6, lane = tid & 63;
  int t = (blockIdx.x << 2) + wv;
  float acc[8] = {0, 0, 0, 0, 0, 0, 0, 0};
#pragma unroll
  for (int k = 0; k < 6; k++) {
    int c = lane + (k << 6);
    float xv = bf2f(xln[(size_t)t * 384 + c]);
#pragma unroll
    for (int e = 0; e < 8; e++) acc[e] += xv * gwl[e * 384 + c];
  }
#pragma unroll
  for (int off = 32; off > 0; off >>= 1) {
#pragma unroll
    for (int e = 0; e < 8; e++) acc[e] += __shfl_xor(acc[e], off, 64);
  }
  if (lane == 0) {
    float v1 = -1e30f, v2 = -1e30f;
    int e1 = 0, e2 = 0;
#pragma unroll
    for (int e = 0; e < 8; e++) {
      float l = acc[e];
      if (l > v1) { v2 = v1; e2 = e1; v1 = l; e1 = e; }
      else if (l > v2) { v2 = l; e2 = e; }
    }
    float sum = 0.f;
#pragma unroll
    for (int e = 0; e < 8; e++) sum += __expf(acc[e] - v1);
    float p = 1.0f / sum;               // = max softmax prob
    float ew = __expf(v2 - v1);
    float w1 = 1.0f / (1.0f + ew);
    keys[t] = ~__float_as_uint(p);      // ascending sort == descending priority, stable
    vals[t] = (u32)t;
    topi[t] = (u32)e1 | ((u32)e2 << 8);
    g1[t] = w1;
    g2[t] = ew * w1;
  }
}

// ---------------- stable counting-sort machinery (8-bit digit) ----------------
__global__ __launch_bounds__(256) void k_hist(const u32* __restrict__ keys,
                                              u32* __restrict__ hist, int shift) {
  __shared__ u32 h[256];
  int tid = threadIdx.x;
  h[tid] = 0;
  __syncthreads();
  u32 key = keys[((size_t)blockIdx.x << 8) + tid];
  atomicAdd(&h[(key >> shift) & 255u], 1u);
  __syncthreads();
  hist[(size_t)tid * gridDim.x + blockIdx.x] = h[tid];
}

// row-local exclusive scan: one block per digit row of `nb` per-block counts.
__global__ __launch_bounds__(256) void k_scan_rows(u32* __restrict__ data,
                                                   u32* __restrict__ totals, int nb) {
  __shared__ u32 ws[256];
  int d = blockIdx.x, tid = threadIdx.x;
  int seg = nb >> 8;  // 1 or 2
  u32 base = (u32)d * nb + tid * seg;
  u32 v[2] = {0, 0};
  u32 s = 0;
  for (int i = 0; i < seg; i++) { v[i] = data[base + i]; s += v[i]; }
  ws[tid] = s;
  __syncthreads();
  for (int dd = 1; dd < 256; dd <<= 1) {
    u32 t = (tid >= dd) ? ws[tid - dd] : 0u;
    __syncthreads();
    ws[tid] += t;
    __syncthreads();
  }
  if (tid == 255) totals[d] = ws[255];
  u32 run = (tid > 0) ? ws[tid - 1] : 0u;
  for (int i = 0; i < seg; i++) {
    u32 tmp = v[i];
    data[base + i] = run;
    run += tmp;
  }
}

// exclusive scan of the 256 digit totals -> dbase
__global__ __launch_bounds__(256) void k_scan_digits(const u32* __restrict__ totals,
                                                     u32* __restrict__ dbase) {
  __shared__ u32 ws[256];
  int tid = threadIdx.x;
  ws[tid] = totals[tid];
  __syncthreads();
  for (int dd = 1; dd < 256; dd <<= 1) {
    u32 t = (tid >= dd) ? ws[tid - dd] : 0u;
    __syncthreads();
    ws[tid] += t;
    __syncthreads();
  }
  dbase[tid] = (tid > 0) ? ws[tid - 1] : 0u;
}

// stable scatter with ballot-based local rank (4 waves x 256 digits)
__global__ __launch_bounds__(256) void k_scatter(const u32* __restrict__ kin,
                                                 const u32* __restrict__ vin,
                                                 u32* __restrict__ kout, u32* __restrict__ vout,
                                                 const u32* __restrict__ scanned,
                                                 const u32* __restrict__ dbase, int shift) {
  __shared__ u32 cnt[4 * 256];
  int tid = threadIdx.x;
  int w = tid >> 6, l = tid & 63;
  int g = (blockIdx.x << 8) + tid;
  u32 key = kin[g], val = vin[g];
  u32 d = (key >> shift) & 255u;
  for (int i = tid; i < 1024; i += 256) cnt[i] = 0u;
  __syncthreads();
  u64 match = ~0ull;
#pragma unroll
  for (int b = 0; b < 8; b++) {
    int bit = (d >> b) & 1;
    u64 bal = __ballot(bit);
    match &= bit ? bal : ~bal;
  }
  u32 rw = __popcll(match & ((1ull << l) - 1ull));
  if (rw == 0) cnt[(w << 8) + d] = (u32)__popcll(match);
  __syncthreads();
  u32 pre = 0;
  for (int w2 = 0; w2 < w; w2++) pre += cnt[(w2 << 8) + d];
  u32 pos = dbase[d] + scanned[(size_t)d * gridDim.x + blockIdx.x] + pre + rw;
  kout[pos] = key;
  vout[pos] = val;
}

// build k-major entry list over priority-sorted tokens
__global__ __launch_bounds__(256) void k_entries(const u32* __restrict__ order,
                                                 const u32* __restrict__ topi,
                                                 const float* __restrict__ g1,
                                                 const float* __restrict__ g2,
                                                 u32* __restrict__ ee, u32* __restrict__ et,
                                                 float* __restrict__ eg) {
  int m = (blockIdx.x << 8) + threadIdx.x;
  int i = m & 65535, k = m >> 16;
  u32 tok = order[i];
  u32 pk = topi[tok];
  ee[m] = k ? ((pk >> 8) & 255u) : (pk & 255u);
  et[m] = tok;
  eg[m] = k ? g2[tok] : g1[tok];
}

// stable counting sort by expert + capacity truncation -> dispatch tables + inverse map
__global__ __launch_bounds__(256) void k_dispatch(const u32* __restrict__ ee,
                                                  const u32* __restrict__ et,
                                                  const float* __restrict__ eg,
                                                  const u32* __restrict__ scanned,
                                                  int* __restrict__ dtok, float* __restrict__ dgate,
                                                  int* __restrict__ inv) {
  __shared__ u32 cnt[4 * 8];
  int tid = threadIdx.x;
  int w = tid >> 6, l = tid & 63;
  int m = (blockIdx.x << 8) + tid;
  u32 e = ee[m];
  if (tid < 32) cnt[tid] = 0u;
  __syncthreads();
  u64 match = ~0ull;
#pragma unroll
  for (int b = 0; b < 3; b++) {
    int bit = (e >> b) & 1;
    u64 bal = __ballot(bit);
    match &= bit ? bal : ~bal;
  }
  u32 rw = __popcll(match & ((1ull << l) - 1ull));
  if (rw == 0) cnt[(w << 3) + e] = (u32)__popcll(match);
  __syncthreads();
  u32 pre = 0;
  for (int w2 = 0; w2 < w; w2++) pre += cnt[(w2 << 3) + e];
  u32 pos = scanned[(size_t)e * gridDim.x + blockIdx.x] + pre + rw;
  if (pos < (u32)BE) {
    int slot = (int)e * BP + (int)pos;
    dtok[slot] = (int)et[m];
    dgate[slot] = eg[m];
    inv[et[m] * 2 + (m >> 16)] = slot;
  }
}

// ---------------- fp32 -> bf16 transposed weight prep: in [E][R][S] -> out [E][S][R] ----------------
__global__ __launch_bounds__(256) void k_transpose_bf16(const float* __restrict__ in,
                                                        u16* __restrict__ out, int R, int S) {
  __shared__ float t[32][33];
  int e = blockIdx.z;
  const float* ip = in + (size_t)e * R * S;
  u16* op = out + (size_t)e * R * S;
  int s0 = blockIdx.x << 5, r0 = blockIdx.y << 5;
  int tx = threadIdx.x, ty = threadIdx.y;
#pragma unroll
  for (int i = 0; i < 4; i++) {
    int r = r0 + ty + (i << 3);
    t[ty + (i << 3)][tx] = ip[(size_t)r * S + s0 + tx];
  }
  __syncthreads();
#pragma unroll
  for (int i = 0; i < 4; i++) {
    int s = s0 + ty + (i << 3);
    op[(size_t)s * R + r0 + tx] = f2bf(t[tx][ty + (i << 3)]);
  }
}

// ---------------- GEMM1: hid = gelu(gather(xln) @ w1 + b1), 128x128x32 MFMA tiles ----------------
__global__ __launch_bounds__(256) void k_gemm1(const u16* __restrict__ xln,
                                               const u16* __restrict__ w1t,
                                               const float* __restrict__ b1,
                                               const int* __restrict__ dtok,
                                               u16* __restrict__ hid, int e0) {
  __shared__ __align__(16) char smem[35072];  // staging 16KB; reused as 128x136 bf16 repack
  short* As = (short*)smem;
  short* Bs = (short*)(smem + 8192);
  int tid = threadIdx.x;
  int bx = blockIdx.x, by = blockIdx.y, z = blockIdx.z;
  int e = e0 + z;
  int f1 = tid, f2 = tid + 256;
  int m1 = ((f1 >> 6) << 4) | (f1 & 15), kq1 = (f1 >> 4) & 3;
  int m2 = ((f2 >> 6) << 4) | (f2 & 15), kq2 = (f2 >> 4) & 3;
  int dbase = e * BP + (bx << 7);
  int tokA1 = dtok[dbase + m1];
  int tokA2 = dtok[dbase + m2];
  const u16* a1p = xln + (size_t)tokA1 * 384 + kq1 * 8;
  const u16* a2p = xln + (size_t)tokA2 * 384 + kq2 * 8;
  const u16* bb = w1t + ((size_t)e * HD + (by << 7)) * 384;
  const u16* bp1 = bb + (size_t)m1 * 384 + kq1 * 8;
  const u16* bp2 = bb + (size_t)m2 * 384 + kq2 * 8;
  int wv = tid >> 6, lane = tid & 63;
  int wm = wv & 1, wn = wv >> 1;
  f32x4 acc[4][4];
#pragma unroll
  for (int i = 0; i < 4; i++)
#pragma unroll
    for (int j = 0; j < 4; j++) acc[i][j] = (f32x4){0.f, 0.f, 0.f, 0.f};
  for (int kk = 0; kk < 12; kk++) {
    gl16(a1p + kk * 32, &As[f1 * 8]);
    gl16(a2p + kk * 32, &As[f2 * 8]);
    gl16(bp1 + kk * 32, &Bs[f1 * 8]);
    gl16(bp2 + kk * 32, &Bs[f2 * 8]);
    __syncthreads();
    bf16x8 af[4], bfr[4];
#pragma unroll
    for (int i = 0; i < 4; i++) af[i] = *(const bf16x8*)&As[((((wm << 2) + i) << 6) | lane) * 8];
#pragma unroll
    for (int j = 0; j < 4; j++) bfr[j] = *(const bf16x8*)&Bs[((((wn << 2) + j) << 6) | lane) * 8];
#pragma unroll
    for (int i = 0; i < 4; i++)
#pragma unroll
      for (int j = 0; j < 4; j++)
        acc[i][j] = __builtin_amdgcn_mfma_f32_16x16x32_bf16(af[i], bfr[j], acc[i][j], 0, 0, 0);
    __syncthreads();
  }
  int quad = lane >> 4, c15 = lane & 15;
  u16* rp = (u16*)smem;  // [128][136]
#pragma unroll
  for (int j = 0; j < 4; j++) {
    int col = (((wn << 2) + j) << 4) | c15;
    float bias = b1[e * HD + (by << 7) + col];
#pragma unroll
    for (int i = 0; i < 4; i++) {
      int row = (((wm << 2) + i) << 4) + (quad << 2);
#pragma unroll
      for (int v = 0; v < 4; v++) {
        float val = acc[i][j][v] + bias;
        val = val / (1.0f + __expf(-1.702f * val));  // sigmoid-gelu (err ~0.02 -> ~1e-8 in output)
        rp[(row + v) * 136 + col] = f2bf(val);
      }
    }
  }
  __syncthreads();
  u16* hb = hid + (size_t)z * BP * HD + ((size_t)(bx << 7)) * HD + (by << 7);
#pragma unroll
  for (int it = 0; it < 4; it++) {
    int q = tid + (it << 8);
    int r = q >> 4, cc = (q & 15) << 3;
    *(uint4*)&hb[(size_t)r * HD + cc] = *(const uint4*)&rp[r * 136 + cc];
  }
}

// ---------------- GEMM2: y = (hid @ w2 + b2) * gate (bf16 out) ----------------
__global__ __launch_bounds__(256) void k_gemm2(const u16* __restrict__ hid,
                                               const u16* __restrict__ w2t,
                                               const float* __restrict__ b2,
                                               const float* __restrict__ dgate,
                                               u16* __restrict__ yb, int e0) {
  __shared__ __align__(16) char smem[35072];
  __shared__ float gates[128];
  short* As = (short*)smem;
  short* Bs = (short*)(smem + 8192);
  int tid = threadIdx.x;
  int bx = blockIdx.x, by = blockIdx.y, z = blockIdx.z;
  int e = e0 + z;
  if (tid < 128) gates[tid] = dgate[e * BP + (bx << 7) + tid];
  int f1 = tid, f2 = tid + 256;
  int m1 = ((f1 >> 6) << 4) | (f1 & 15), kq1 = (f1 >> 4) & 3;
  int m2 = ((f2 >> 6) << 4) | (f2 & 15), kq2 = (f2 >> 4) & 3;
  const u16* ab = hid + (size_t)(z * BP + (bx << 7)) * HD;
  const u16* a1p = ab + (size_t)m1 * HD + kq1 * 8;
  const u16* a2p = ab + (size_t)m2 * HD + kq2 * 8;
  const u16* bb = w2t + ((size_t)e * 384 + (by << 7)) * HD;
  const u16* bp1 = bb + (size_t)m1 * HD + kq1 * 8;
  const u16* bp2 = bb + (size_t)m2 * HD + kq2 * 8;
  int wv = tid >> 6, lane = tid & 63;
  int wm = wv & 1, wn = wv >> 1;
  f32x4 acc[4][4];
#pragma unroll
  for (int i = 0; i < 4; i++)
#pragma unroll
    for (int j = 0; j < 4; j++) acc[i][j] = (f32x4){0.f, 0.f, 0.f, 0.f};
  for (int kk = 0; kk < 48; kk++) {
    gl16(a1p + kk * 32, &As[f1 * 8]);
    gl16(a2p + kk * 32, &As[f2 * 8]);
    gl16(bp1 + kk * 32, &Bs[f1 * 8]);
    gl16(bp2 + kk * 32, &Bs[f2 * 8]);
    __syncthreads();
    bf16x8 af[4], bfr[4];
#pragma unroll
    for (int i = 0; i < 4; i++) af[i] = *(const bf16x8*)&As[((((wm << 2) + i) << 6) | lane) * 8];
#pragma unroll
    for (int j = 0; j < 4; j++) bfr[j] = *(const bf16x8*)&Bs[((((wn << 2) + j) << 6) | lane) * 8];
#pragma unroll
    for (int i = 0; i < 4; i++)
#pragma unroll
      for (int j = 0; j < 4; j++)
        acc[i][j] = __builtin_amdgcn_mfma_f32_16x16x32_bf16(af[i], bfr[j], acc[i][j], 0, 0, 0);
    __syncthreads();
  }
  int quad = lane >> 4, c15 = lane & 15;
  u16* rp = (u16*)smem;  // [128][136]
#pragma unroll
  for (int j = 0; j < 4; j++) {
    int col = (((wn << 2) + j) << 4) | c15;
    float bias = b2[e * 384 + (by << 7) + col];
#pragma unroll
    for (int i = 0; i < 4; i++) {
      int row = (((wm << 2) + i) << 4) + (quad << 2);
#pragma unroll
      for (int v = 0; v < 4; v++) {
        float val = (acc[i][j][v] + bias) * gates[row + v];
        rp[(row + v) * 136 + col] = f2bf(val);
      }
    }
  }
  __syncthreads();
  u16* ybb = yb + (size_t)(e * BP + (bx << 7)) * 384 + (by << 7);
#pragma unroll
  for (int it = 0; it < 4; it++) {
    int q = tid + (it << 8);
    int r = q >> 4, cc = (q & 15) << 3;
    *(uint4*)&ybb[(size_t)r * 384 + cc] = *(const uint4*)&rp[r * 136 + cc];
  }
}

// ---------------- combine: out = x + ls * (gathered y rows), NHWC->NCHW via LDS ----------------
__global__ __launch_bounds__(256) void k_final(const float* __restrict__ x,
                                               const u16* __restrict__ yb,
                                               const int* __restrict__ inv,
                                               const float* __restrict__ ls,
                                               float* __restrict__ out) {
  __shared__ float tile[32 * 385];  // [w][c], stride 385 (%32==1) -> conflict-free transpose read
  __shared__ int sl[64];
  int nb = blockIdx.x;  // n*32 + y
  int n = nb >> 5, yy = nb & 31;
  int tid = threadIdx.x;
  int t0 = nb << 5;
  if (tid < 64) sl[tid] = inv[t0 * 2 + tid];
  __syncthreads();
  // register-accumulated vectorized gather: 1536 chunks of 8 bf16
  for (int idx = tid; idx < 1536; idx += 256) {
    int w = idx / 48;
    int cc = (idx - w * 48) << 3;
    float a[8] = {0, 0, 0, 0, 0, 0, 0, 0};
#pragma unroll
    for (int k = 0; k < 2; k++) {
      int s = sl[(w << 1) + k];
      if (s >= 0) {
        uint4 v = *(const uint4*)&yb[(size_t)s * 384 + cc];
        const u16* pv = (const u16*)&v;
#pragma unroll
        for (int j = 0; j < 8; j++) a[j] += bf2f(pv[j]);
      }
    }
    float* tp = &tile[w * 385 + cc];
#pragma unroll
    for (int j = 0; j < 8; j++) tp[j] = a[j];
  }
  __syncthreads();
  // transpose out: float4 along w
  for (int i2 = tid; i2 < 3072; i2 += 256) {
    int c = i2 >> 3, w4 = (i2 & 7) << 2;
    size_t o = ((((size_t)n * 384 + c) << 5) + yy) * 32 + w4;
    float4 xv = *(const float4*)&x[o];
    float lsv = ls[c];
    float4 r;
    r.x = xv.x + lsv * tile[(w4 + 0) * 385 + c];
    r.y = xv.y + lsv * tile[(w4 + 1) * 385 + c];
    r.z = xv.z + lsv * tile[(w4 + 2) * 385 + c];
    r.w = xv.w + lsv * tile[(w4 + 3) * 385 + c];
    *(float4*)&out[o] = r;
  }
}

extern "C" void kernel_launch(void* const* d_in, const int* in_sizes, int n_in,
                              void* d_out, int out_size, void* d_ws, size_t ws_size,
                              hipStream_t stream) {
  (void)in_sizes; (void)n_in; (void)out_size; (void)ws_size;
  const float* x     = (const float*)d_in[0];
  const float* convw = (const float*)d_in[1];
  const float* convb = (const float*)d_in[2];
  const float* lng   = (const float*)d_in[3];
  const float* lnb   = (const float*)d_in[4];
  const float* gw    = (const float*)d_in[5];
  const float* w1    = (const float*)d_in[6];
  const float* b1    = (const float*)d_in[7];
  const float* w2    = (const float*)d_in[8];
  const float* b2    = (const float*)d_in[9];
  const float* ls    = (const float*)d_in[10];
  float* out = (float*)d_out;

  char* p = (char*)d_ws;
  size_t o = 0;
  auto alloc = [&](size_t b) { void* r = p + o; o += (b + 255) & ~(size_t)255; return r; };
  u16* xln    = (u16*)alloc((size_t)T_TOK * C_DIM * 2);          // 50.3 MB
  u16* w1t    = (u16*)alloc((size_t)8 * HD * C_DIM * 2);         // 9.4 MB
  u16* w2t    = (u16*)alloc((size_t)8 * HD * C_DIM * 2);         // 9.4 MB
  u16* hid    = (u16*)alloc((size_t)4 * BP * HD * 2);            // 162 MB (also aliased as conv out)
  u16* yb     = (u16*)alloc((size_t)8 * BP * 384 * 2);           // 81 MB
  u32* keysA  = (u32*)alloc((size_t)T_TOK * 4);
  u32* keysB  = (u32*)alloc((size_t)T_TOK * 4);
  u32* valsA  = (u32*)alloc((size_t)T_TOK * 4);
  u32* valsB  = (u32*)alloc((size_t)T_TOK * 4);
  u32* topi   = (u32*)alloc((size_t)T_TOK * 4);
  float* g1   = (float*)alloc((size_t)T_TOK * 4);
  float* g2   = (float*)alloc((size_t)T_TOK * 4);
  u32* hist   = (u32*)alloc((size_t)256 * 512 * 4);
  u32* totals = (u32*)alloc((size_t)256 * 4);
  u32* dbase  = (u32*)alloc((size_t)256 * 4);
  u32* ee     = (u32*)alloc((size_t)131072 * 4);
  u32* et     = (u32*)alloc((size_t)131072 * 4);
  float* eg   = (float*)alloc((size_t)131072 * 4);
  int* dtok   = (int*)alloc((size_t)8 * BP * 4);
  float* dgate= (float*)alloc((size_t)8 * BP * 4);
  int* inv    = (int*)alloc((size_t)T_TOK * 2 * 4);

  float* hconv = (float*)hid;  // alias: conv output consumed by k_ln before GEMM1 writes hid

  k_conv<<<24576, 256, 0, stream>>>(x, convw, convb, hconv);
  k_ln<<<2048, 256, 0, stream>>>(hconv, lng, lnb, xln);
  k_router<<<16384, 256, 0, stream>>>(xln, gw, keysA, valsA, topi, g1, g2);

  // stable radix sort by ~bits(priority): 4 x 8-bit passes, ends back in keysA/valsA
  u32 *ki = keysA, *vi = valsA, *ko = keysB, *vo = valsB;
  for (int pass = 0; pass < 4; pass++) {
    int shift = pass * 8;
    k_hist<<<256, 256, 0, stream>>>(ki, hist, shift);
    k_scan_rows<<<256, 256, 0, stream>>>(hist, totals, 256);
    k_scan_digits<<<1, 256, 0, stream>>>(totals, dbase);
    k_scatter<<<256, 256, 0, stream>>>(ki, vi, ko, vo, hist, dbase, shift);
    u32* t1 = ki; ki = ko; ko = t1;
    u32* t2 = vi; vi = vo; vo = t2;
  }
  k_entries<<<512, 256, 0, stream>>>(vi, topi, g1, g2, ee, et, eg);
  k_hist<<<512, 256, 0, stream>>>(ee, hist, 0);
  k_scan_rows<<<256, 256, 0, stream>>>(hist, totals, 512);
  hipMemsetAsync(dtok, 0, (size_t)8 * BP * 4, stream);
  hipMemsetAsync(dgate, 0, (size_t)8 * BP * 4, stream);
  hipMemsetAsync(inv, 0xFF, (size_t)T_TOK * 2 * 4, stream);
  k_dispatch<<<512, 256, 0, stream>>>(ee, et, eg, hist, dtok, dgate, inv);

  k_transpose_bf16<<<dim3(48, 12, 8), dim3(32, 8), 0, stream>>>(w1, w1t, 384, 1536);
  k_transpose_bf16<<<dim3(12, 48, 8), dim3(32, 8), 0, stream>>>(w2, w2t, 1536, 384);

  for (int g = 0; g < 2; g++) {
    k_gemm1<<<dim3(103, 12, 4), 256, 0, stream>>>(xln, w1t, b1, dtok, hid, g * 4);
    k_gemm2<<<dim3(103, 3, 4), 256, 0, stream>>>(hid, w2t, b2, dgate, yb, g * 4);
  }
  k_final<<<2048, 256, 0, stream>>>(x, yb, inv, ls, out);
}